// Round 1
// baseline (815.892 us; speedup 1.0000x reference)
//
#include <hip/hip_runtime.h>

// Problem constants (IcoUpSampleMaxIndexLayer)
#define NB    16      // batch
#define CIN   256
#define COUT  128
#define VRAW  10242
#define NVERT 40962
#define HALF  20481   // NVERT / 2 target-range split per scatter block

typedef __attribute__((ext_vector_type(8))) short short8;
typedef __attribute__((ext_vector_type(4))) float floatx4;

__device__ inline unsigned short f2bf(float f) {
    unsigned u = __builtin_bit_cast(unsigned, f);
    u += 0x7fffu + ((u >> 16) & 1u);   // RNE
    return (unsigned short)(u >> 16);
}

// ---- Kernel 0: convert W (128x256 fp32) to bf16 in ws ----
__global__ __launch_bounds__(256) void convw_kernel(const float* __restrict__ W,
                                                    unsigned short* __restrict__ Wbf) {
    int i = blockIdx.x * 256 + threadIdx.x;   // 32768 elements
    Wbf[i] = f2bf(W[i]);
}

// ---- Kernel 1: h[b,o,v] = sum_c W[o,c] x[b,c,v] + bias[o], bf16 MFMA ----
// grid (ceil(VRAW/128), NB), block 256 (4 waves). Wave: all 128 o x 32 v.
__global__ __launch_bounds__(256) void gemm_kernel(const float* __restrict__ x,
                                                   const unsigned short* __restrict__ Wbf,
                                                   const float* __restrict__ bias,
                                                   float* __restrict__ h) {
    const int b    = blockIdx.y;
    const int v0   = blockIdx.x * 128;
    const int wave = threadIdx.x >> 6;
    const int lane = threadIdx.x & 63;
    const int mn   = lane & 15;   // A-row (o within 16-tile) and B-col (v within 16-tile)
    const int q    = lane >> 4;   // quad: k-offset q*8 for A/B, row-offset q*4 for C/D

    const int vw = v0 + wave * 32;

    floatx4 acc[8][2];
#pragma unroll
    for (int ot = 0; ot < 8; ot++) { acc[ot][0] = (floatx4)0.f; acc[ot][1] = (floatx4)0.f; }

#pragma unroll
    for (int ck = 0; ck < 8; ck++) {   // K chunks of 32
        const int c0 = ck * 32;
        short8 bfrag[2];
#pragma unroll
        for (int vt = 0; vt < 2; vt++) {
            const int v   = vw + vt * 16 + mn;
            const bool ok = v < VRAW;
            const float* xp = x + ((size_t)b * CIN + (c0 + q * 8)) * VRAW + v;
#pragma unroll
            for (int j = 0; j < 8; j++) {
                float xv = ok ? xp[(size_t)j * VRAW] : 0.f;
                bfrag[vt][j] = (short)f2bf(xv);
            }
        }
#pragma unroll
        for (int ot = 0; ot < 8; ot++) {
            // A-frag: W[o = ot*16+mn][c0 + q*8 .. +7], 16B contiguous, L2-resident
            short8 afrag = *(const short8*)(Wbf + (ot * 16 + mn) * CIN + c0 + q * 8);
            acc[ot][0] = __builtin_amdgcn_mfma_f32_16x16x32_bf16(afrag, bfrag[0], acc[ot][0], 0, 0, 0);
            acc[ot][1] = __builtin_amdgcn_mfma_f32_16x16x32_bf16(afrag, bfrag[1], acc[ot][1], 0, 0, 0);
        }
    }

#pragma unroll
    for (int ot = 0; ot < 8; ot++) {
#pragma unroll
        for (int vt = 0; vt < 2; vt++) {
            const int v = vw + vt * 16 + mn;
            if (v < VRAW) {
#pragma unroll
                for (int r = 0; r < 4; r++) {
                    const int o = ot * 16 + q * 4 + r;   // C/D: row = quad*4 + reg
                    h[((size_t)b * COUT + o) * VRAW + v] = acc[ot][vt][r] + bias[o];
                }
            }
        }
    }
}

// ---- Kernel 2: dedup (last v wins) + full coalesced y write ----
// grid = 2 * NB * COUT blocks; block owns row r = blockIdx.x>>1, targets
// [tbase, tbase+HALF). Phase 1: stamp[t] = max(v+1) via 16-bit packed CAS-max.
// Phase 2: y[r][t] = stamp ? h[r][stamp-1] : 0  (covers all of y -> no memset).
__global__ __launch_bounds__(1024) void scatter_kernel(const int* __restrict__ up,
                                                       const int* __restrict__ down,
                                                       const int* __restrict__ mpi,
                                                       const float* __restrict__ h,
                                                       float* __restrict__ y) {
    __shared__ unsigned st[(HALF + 1) / 2];   // 10241 dwords = ~40KB
    const int r     = blockIdx.x >> 1;
    const int tbase = (blockIdx.x & 1) * HALF;
    const int tid   = threadIdx.x;

    for (int i = tid; i < (HALF + 1) / 2; i += 1024) st[i] = 0u;
    __syncthreads();

    const int* mpiRow = mpi + (size_t)r * VRAW;
    for (int v = tid; v < VRAW; v += 1024) {
        const int k = mpiRow[v];
        const int t = up[down[v] * 7 + k];
        const unsigned lt = (unsigned)(t - tbase);
        if (lt < (unsigned)HALF) {
            const unsigned val = (unsigned)(v + 1);
            const unsigned sh  = (lt & 1u) * 16u;
            unsigned* p = &st[lt >> 1];
            unsigned old = *p;
            while (true) {
                unsigned cur = (old >> sh) & 0xffffu;
                if (cur >= val) break;
                unsigned nw = (old & ~(0xffffu << sh)) | (val << sh);
                unsigned prev = atomicCAS(p, old, nw);
                if (prev == old) break;
                old = prev;
            }
        }
    }
    __syncthreads();

    const float* hRow = h + (size_t)r * VRAW;
    float* yRow = y + (size_t)r * NVERT + tbase;
    for (int lt = tid; lt < HALF; lt += 1024) {
        const unsigned s = (st[(unsigned)lt >> 1] >> (((unsigned)lt & 1u) * 16u)) & 0xffffu;
        yRow[lt] = s ? hRow[s - 1] : 0.0f;
    }
}

extern "C" void kernel_launch(void* const* d_in, const int* in_sizes, int n_in,
                              void* d_out, int out_size, void* d_ws, size_t ws_size,
                              hipStream_t stream) {
    const float* x    = (const float*)d_in[0];
    const float* W    = (const float*)d_in[1];
    const float* bias = (const float*)d_in[2];
    const int*   up   = (const int*)d_in[3];   // (NVERT, 7)
    const int*   down = (const int*)d_in[4];   // (VRAW,)
    const int*   mpi  = (const int*)d_in[5];   // (NB, COUT, VRAW)
    float* y = (float*)d_out;

    // ws layout: [0, 64KB) Wbf bf16; then h fp32 (NB*COUT*VRAW floats = ~84MB)
    unsigned short* Wbf = (unsigned short*)d_ws;
    float* h = (float*)((char*)d_ws + 65536);

    convw_kernel<<<COUT * CIN / 256, 256, 0, stream>>>(W, Wbf);

    dim3 ggrid((VRAW + 127) / 128, NB);
    gemm_kernel<<<ggrid, 256, 0, stream>>>(x, Wbf, bias, h);

    scatter_kernel<<<NB * COUT * 2, 1024, 0, stream>>>(up, down, mpi, h, y);
}